// Round 11
// baseline (3940.025 us; speedup 1.0000x reference)
//
#include <hip/hip_runtime.h>
#include <cstdint>
#include <cstddef>

// BinaryTreeLSTM — fused bf16 MFMA GEMMs.
// Leaf:  gemm_leaff (round-9 proven: 4-wave, 2 blocks/CU, period-48 wfxP).
// Nodes n=256/128/64: gemm320w — 256x320 block, 4 waves (2Mx2N), wave 128x160:
//   31% fewer LDS-read bytes per MFMA than the 8-wave 128x80 layout.
//   4 LDS slots, lookahead 3, vmcnt ladder 18/9/0 (only ever waits for loads
//   >=2 phases old — round-10 lesson). Single barrier per phase (round-6).
// Tail n<=32: gemm256 split-K (bf16 partials) + node_gates (period-80).

typedef __attribute__((ext_vector_type(8))) short bf16x8;
typedef __attribute__((ext_vector_type(4))) float f32x4;

__device__ __forceinline__ float sig_(float x) { return 1.0f / (1.0f + __expf(-x)); }

__device__ __forceinline__ unsigned short f2bf_(float x) {
    union { float f; uint32_t u; } v; v.f = x;
    uint32_t r = v.u + 0x7fffu + ((v.u >> 16) & 1u);   // RNE
    return (unsigned short)(r >> 16);
}
__device__ __forceinline__ float bf2f_(unsigned short u) {
    union { uint32_t u; float f; } v; v.u = ((uint32_t)u) << 16; return v.f;
}

#define GL16(g, l) __builtin_amdgcn_global_load_lds( \
    (const __attribute__((address_space(1))) void*)(g), \
    (__attribute__((address_space(3))) void*)(l), 16, 0, 0)

// ---------------------------------------------------------------------------
// gemm320w: fused internal level. A[M,2048]bf16, Wp[5120,2048]bf16 period-80
// (row t*80+g*16+jj <-> gate g of j=t*16+jj). Block 256x320, 256 thr = 4
// waves (2Mx2N), wave 128x160 (= 2 j-subgroups x 5 gates x 16 j). acc[8][10].
// LDS 4 slots x (16KB A + 20KB B) = 144 KB, 1 block/CU. 9 GL16/thread/phase.
// Ladder: steady vmcnt(18) = kh p+1 (3 phases old); drain 9 -> 0.
// W-stationary decode: gx=16 -> 2 bx per XCD. M multiple of 256.
// ---------------------------------------------------------------------------
__global__ __launch_bounds__(256, 1)
void gemm320w(const unsigned short* __restrict__ A,
              const unsigned short* __restrict__ Wp,
              const float* __restrict__ b,
              const unsigned short* __restrict__ c_prev,
              unsigned short* __restrict__ c_out,
              unsigned short* __restrict__ h_out,
              int M)
{
    __shared__ unsigned short lA[4 * 8192];    // 64 KB (slot 16 KB = [256][32])
    __shared__ unsigned short lB[4 * 10240];   // 80 KB (slot 20 KB = [320][32])
    const int lda = 2048;

    const int orig = blockIdx.x + 16 * blockIdx.y;
    const int xcd  = orig & 7;
    const int pos  = orig >> 3;
    const int bx   = xcd * 2 + (pos & 1);
    const int by   = pos >> 1;

    const int tid = threadIdx.x;
    const int ln  = tid & 63;
    const int wv  = tid >> 6;        // 0..3
    const int wrp = wv >> 1;         // 0..1 : rows wrp*128
    const int wnp = wv & 1;          // 0..1 : B-rows wnp*160 (32 j)
    const int row0 = by * 256;
    const int colb = bx * 320;

    // staging: pass q covers slot rows q*64..q*64+63; thread -> row (tid>>2)+q*64
    const int rowS = tid >> 2;                        // 0..63
    const int gS   = (tid & 3) ^ ((tid >> 3) & 3);    // pass-invariant swizzle slot
    const unsigned short* aP[4];
    const unsigned short* wP[5];
    #pragma unroll
    for (int q = 0; q < 4; ++q)
        aP[q] = A + (size_t)min(row0 + rowS + q * 64, M - 1) * lda + gS * 8;
    #pragma unroll
    for (int q = 0; q < 5; ++q)
        wP[q] = Wp + (size_t)(colb + rowS + q * 64) * lda + gS * 8;
    const int ldq = tid * 8;   // + q*2048 per pass

    int offA[8], offB[10];
    #pragma unroll
    for (int i = 0; i < 8; ++i) {
        const int r = wrp * 128 + i * 16 + (ln & 15);
        offA[i] = r * 32 + ((ln >> 4) ^ ((r >> 1) & 3)) * 8;
    }
    #pragma unroll
    for (int i = 0; i < 10; ++i) {
        const int r = wnp * 160 + i * 16 + (ln & 15);   // i = gg*5 + g
        offB[i] = r * 32 + ((ln >> 4) ^ ((r >> 1) & 3)) * 8;
    }

    f32x4 acc[8][10] = {};
    const int P = 64;   // K = 2048

#define ISSUE_W(kh) do { \
    const int _sl = (kh) & 3; \
    const size_t _ko = (size_t)(kh) * 32; \
    GL16(aP[0] + _ko, lA + _sl * 8192 + ldq); \
    GL16(aP[1] + _ko, lA + _sl * 8192 + 2048 + ldq); \
    GL16(aP[2] + _ko, lA + _sl * 8192 + 4096 + ldq); \
    GL16(aP[3] + _ko, lA + _sl * 8192 + 6144 + ldq); \
    GL16(wP[0] + _ko, lB + _sl * 10240 + ldq); \
    GL16(wP[1] + _ko, lB + _sl * 10240 + 2048 + ldq); \
    GL16(wP[2] + _ko, lB + _sl * 10240 + 4096 + ldq); \
    GL16(wP[3] + _ko, lB + _sl * 10240 + 6144 + ldq); \
    GL16(wP[4] + _ko, lB + _sl * 10240 + 8192 + ldq); \
} while (0)

    ISSUE_W(0); ISSUE_W(1); ISSUE_W(2);
    asm volatile("s_waitcnt vmcnt(18)" ::: "memory");   // kh0 landed
    asm volatile("s_barrier" ::: "memory");

    for (int p = 0; p < P; ++p) {
        const unsigned short* pa = lA + (p & 3) * 8192;
        const unsigned short* pb = lB + (p & 3) * 10240;
        bf16x8 bf[10], af[8];
        #pragma unroll
        for (int i = 0; i < 10; ++i) bf[i] = *(const bf16x8*)(pb + offB[i]);
        #pragma unroll
        for (int i = 0; i < 8; ++i)  af[i] = *(const bf16x8*)(pa + offA[i]);
        if (p <= P - 4) ISSUE_W(p + 3);
        __builtin_amdgcn_s_setprio(1);
        #pragma unroll
        for (int m = 0; m < 8; ++m)
            #pragma unroll
            for (int i = 0; i < 10; ++i)
                acc[m][i] = __builtin_amdgcn_mfma_f32_16x16x32_bf16(af[m], bf[i], acc[m][i], 0, 0, 0);
        __builtin_amdgcn_s_setprio(0);
        if (p <= P - 4)      asm volatile("s_waitcnt vmcnt(18)" ::: "memory"); // kh p+1 (3 phases old)
        else if (p == P - 3) asm volatile("s_waitcnt vmcnt(9)"  ::: "memory"); // kh P-2
        else if (p == P - 2) asm volatile("s_waitcnt vmcnt(0)"  ::: "memory"); // kh P-1
        if (p < P - 1) asm volatile("s_barrier" ::: "memory");
    }
#undef ISSUE_W

    // ---- fused node-gate epilogue: i = gg*5 + g ----
    #pragma unroll
    for (int gg = 0; gg < 2; ++gg) {
        const int jg = bx * 64 + wnp * 32 + gg * 16 + (ln & 15);   // j in [0,1024)
        const float bi = b[1024 + jg];
        const float bo = b[2048 + jg];
        const float bu = b[3072 + jg];
        const float bff = b[jg];
        #pragma unroll
        for (int mi = 0; mi < 8; ++mi) {
            #pragma unroll
            for (int rg = 0; rg < 4; ++rg) {
                const int r = row0 + wrp * 128 + mi * 16 + (ln >> 4) * 4 + rg;
                if (r < M) {
                    const float cl = bf2f_(c_prev[(size_t)r * 2048 + jg]);
                    const float cr = bf2f_(c_prev[(size_t)r * 2048 + 1024 + jg]);
                    const float iv = sig_(acc[mi][gg * 5 + 0][rg] + bi);
                    const float ov = sig_(acc[mi][gg * 5 + 1][rg] + bo);
                    const float uv = tanhf(acc[mi][gg * 5 + 2][rg] + bu);
                    const float flv = sig_(acc[mi][gg * 5 + 3][rg] + bff);
                    const float frv = sig_(acc[mi][gg * 5 + 4][rg] + bff);
                    const float c = iv * uv + flv * cl + frv * cr;
                    const float h = ov * tanhf(c);
                    c_out[(size_t)r * 1024 + jg] = f2bf_(c);
                    h_out[(size_t)r * 1024 + jg] = f2bf_(h);
                }
            }
        }
    }
}

// ---------------------------------------------------------------------------
// gemm_leaff: fused LEAF (round-9 verbatim). Wp period-48. Block 128x192,
// 4 waves, LDS 60 KB -> 2 blocks/CU. 3 slots, lookahead 2.
// ---------------------------------------------------------------------------
__global__ __launch_bounds__(256, 2)
void gemm_leaff(const unsigned short* __restrict__ A,
                const unsigned short* __restrict__ Wp,
                const float* __restrict__ b,
                unsigned short* __restrict__ c_out,
                unsigned short* __restrict__ h_out)
{
    __shared__ unsigned short lA[3 * 4096];   // 24 KB
    __shared__ unsigned short lB[3 * 6144];   // 36 KB
    const int lda = 1024;

    const int orig = blockIdx.x + 16 * blockIdx.y;
    const int xcd  = orig & 7;
    const int pos  = orig >> 3;
    const int bx   = xcd * 2 + (pos & 1);
    const int by   = pos >> 1;

    if ((pos >> 5) & 1) asm volatile("s_sleep 10" ::: "memory");

    const int tid = threadIdx.x;
    const int ln  = tid & 63;
    const int wv  = tid >> 6;
    const int wrp = wv >> 1;
    const int wcp = wv & 1;
    const int row0 = by * 128;
    const int colb = bx * 192;

    const int rowS = tid >> 2;
    const int gS   = (tid & 3) ^ ((tid >> 3) & 3);
    const unsigned short* a0 = A + (size_t)(row0 + rowS) * lda + gS * 8;
    const unsigned short* a1 = a0 + (size_t)64 * lda;
    const unsigned short* w0 = Wp + (size_t)(colb + rowS) * lda + gS * 8;
    const unsigned short* w1 = w0 + (size_t)64 * lda;
    const unsigned short* w2 = w0 + (size_t)128 * lda;
    const int ld0 = tid * 8;

    int offA[4], offB[6];
    #pragma unroll
    for (int i = 0; i < 4; ++i) {
        const int r = wrp * 64 + i * 16 + (ln & 15);
        offA[i] = r * 32 + ((ln >> 4) ^ ((r >> 1) & 3)) * 8;
    }
    #pragma unroll
    for (int grp = 0; grp < 2; ++grp)
        #pragma unroll
        for (int g = 0; g < 3; ++g) {
            const int r = wcp * 96 + grp * 48 + g * 16 + (ln & 15);
            offB[grp * 3 + g] = r * 32 + ((ln >> 4) ^ ((r >> 1) & 3)) * 8;
        }

    f32x4 acc[4][6] = {};
    const int P = 32;   // K = 1024

#define ISSUE_L(sl, kh) do { \
    const size_t _ko = (size_t)(kh) * 32; \
    GL16(a0 + _ko, lA + (sl) * 4096 + ld0); \
    GL16(a1 + _ko, lA + (sl) * 4096 + 2048 + ld0); \
    GL16(w0 + _ko, lB + (sl) * 6144 + ld0); \
    GL16(w1 + _ko, lB + (sl) * 6144 + 2048 + ld0); \
    GL16(w2 + _ko, lB + (sl) * 6144 + 4096 + ld0); \
} while (0)

    ISSUE_L(0, 0); ISSUE_L(1, 1);
    asm volatile("s_waitcnt vmcnt(5)" ::: "memory");
    asm volatile("s_barrier" ::: "memory");

    int rd = 0, is = 2;
    for (int p = 0; p < P; ++p) {
        const unsigned short* pa = lA + rd * 4096;
        const unsigned short* pb = lB + rd * 6144;
        bf16x8 bf[6], af[4];
        #pragma unroll
        for (int g = 0; g < 6; ++g) bf[g] = *(const bf16x8*)(pb + offB[g]);
        #pragma unroll
        for (int i = 0; i < 4; ++i) af[i] = *(const bf16x8*)(pa + offA[i]);
        if (p <= P - 3) ISSUE_L(is, p + 2);
        __builtin_amdgcn_s_setprio(1);
        #pragma unroll
        for (int m = 0; m < 4; ++m)
            #pragma unroll
            for (int g = 0; g < 6; ++g)
                acc[m][g] = __builtin_amdgcn_mfma_f32_16x16x32_bf16(af[m], bf[g], acc[m][g], 0, 0, 0);
        __builtin_amdgcn_s_setprio(0);
        if (p <= P - 3)      asm volatile("s_waitcnt vmcnt(5)" ::: "memory");
        else if (p == P - 2) asm volatile("s_waitcnt vmcnt(0)" ::: "memory");
        if (p < P - 1) asm volatile("s_barrier" ::: "memory");
        rd = (rd == 2) ? 0 : rd + 1;
        is = (is == 2) ? 0 : is + 1;
    }
#undef ISSUE_L

    #pragma unroll
    for (int grp = 0; grp < 2; ++grp) {
        const int j = bx * 64 + wcp * 32 + grp * 16 + (ln & 15);
        const float bi = b[1024 + j];
        const float bo = b[2048 + j];
        const float bu = b[3072 + j];
        #pragma unroll
        for (int mi = 0; mi < 4; ++mi) {
            #pragma unroll
            for (int rg = 0; rg < 4; ++rg) {
                const int r = row0 + wrp * 64 + mi * 16 + (ln >> 4) * 4 + rg;
                const float cv = sig_(acc[mi][grp * 3 + 0][rg] + bi) * tanhf(acc[mi][grp * 3 + 2][rg] + bu);
                const float hv = sig_(acc[mi][grp * 3 + 1][rg] + bo) * tanhf(cv);
                c_out[(size_t)r * 1024 + j] = f2bf_(cv);
                h_out[(size_t)r * 1024 + j] = f2bf_(hv);
            }
        }
    }
}

// ---------------------------------------------------------------------------
// gemm256: tail split-K. partial[bz][M,N] bf16 = A[M,kr] @ W[N,kr]^T.
// ---------------------------------------------------------------------------
__global__ __launch_bounds__(512, 2)
void gemm256(const unsigned short* __restrict__ A,
             const unsigned short* __restrict__ W,
             unsigned short* __restrict__ C, int M, int N, int lda, int Klen)
{
    __shared__ unsigned short lA[4 * 8192];   // 64 KB
    __shared__ unsigned short lB[4 * 8192];   // 64 KB

    const int gx = gridDim.x, gy = gridDim.y;
    int id = blockIdx.x + gx * (blockIdx.y + gy * blockIdx.z);
    {
        const int nwg = gx * gy * gridDim.z;
        const int q = nwg >> 3, r = nwg & 7, x = id & 7, i = id >> 3;
        id = (x < r ? x * (q + 1) : r * (q + 1) + (x - r) * q) + i;
    }
    const int bz  = id / (gx * gy);
    const int rem = id - bz * gx * gy;
    const int by  = rem / gx;
    const int bx  = rem - by * gx;

    const int tid = threadIdx.x;
    const int ln  = tid & 63;
    const int wv  = tid >> 6;
    const int wrp = wv >> 2;
    const int wcp = wv & 3;
    const int row0 = by * 256;
    const int colb = bx * 256;
    const int kbase = bz * Klen;
    C += (size_t)bz * M * N;

    const int rowS = tid >> 2;
    const int gS   = (tid & 3) ^ ((tid >> 3) & 3);
    const unsigned short* a0 = A + (size_t)min(row0 + rowS,       M - 1) * lda + kbase + gS * 8;
    const unsigned short* a1 = A + (size_t)min(row0 + rowS + 128, M - 1) * lda + kbase + gS * 8;
    const unsigned short* b0 = W + (size_t)(colb + rowS)       * lda + kbase + gS * 8;
    const unsigned short* b1 = W + (size_t)(colb + rowS + 128) * lda + kbase + gS * 8;
    const int ld0 = tid * 8;
    const int ld1 = tid * 8 + 4096;

    int offA[8], offB[4];
    #pragma unroll
    for (int i = 0; i < 8; ++i) {
        const int r = wrp * 128 + i * 16 + (ln & 15);
        offA[i] = r * 32 + ((ln >> 4) ^ ((r >> 1) & 3)) * 8;
    }
    #pragma unroll
    for (int i = 0; i < 4; ++i) {
        const int r = wcp * 64 + i * 16 + (ln & 15);
        offB[i] = r * 32 + ((ln >> 4) ^ ((r >> 1) & 3)) * 8;
    }

    f32x4 acc[8][4] = {};
    const int P = Klen >> 5;

#define ISSUE_KH(kh) do { \
    const int _sl = (kh) & 3; \
    const size_t _ko = (size_t)(kh) * 32; \
    GL16(a0 + _ko, lA + _sl * 8192 + ld0); \
    GL16(a1 + _ko, lA + _sl * 8192 + ld1); \
    GL16(b0 + _ko, lB + _sl * 8192 + ld0); \
    GL16(b1 + _ko, lB + _sl * 8192 + ld1); \
} while (0)

    ISSUE_KH(0); ISSUE_KH(1); ISSUE_KH(2);
    asm volatile("s_waitcnt vmcnt(8)" ::: "memory");
    asm volatile("s_barrier" ::: "memory");

    for (int p = 0; p < P; ++p) {
        const unsigned short* pa = lA + (p & 3) * 8192;
        const unsigned short* pb = lB + (p & 3) * 8192;
        bf16x8 bf[4], af[4], ag[4];
        #pragma unroll
        for (int i = 0; i < 4; ++i) bf[i] = *(const bf16x8*)(pb + offB[i]);
        #pragma unroll
        for (int i = 0; i < 4; ++i) af[i] = *(const bf16x8*)(pa + offA[i]);
        #pragma unroll
        for (int i = 0; i < 4; ++i) ag[i] = *(const bf16x8*)(pa + offA[4 + i]);
        if (p <= P - 4) ISSUE_KH(p + 3);
        __builtin_amdgcn_s_setprio(1);
        #pragma unroll
        for (int m = 0; m < 4; ++m)
            #pragma unroll
            for (int n = 0; n < 4; ++n)
                acc[m][n] = __builtin_amdgcn_mfma_f32_16x16x32_bf16(af[m], bf[n], acc[m][n], 0, 0, 0);
        #pragma unroll
        for (int m = 0; m < 4; ++m)
            #pragma unroll
            for (int n = 0; n < 4; ++n)
                acc[4 + m][n] = __builtin_amdgcn_mfma_f32_16x16x32_bf16(ag[m], bf[n], acc[4 + m][n], 0, 0, 0);
        __builtin_amdgcn_s_setprio(0);
        if (p <= P - 4)      asm volatile("s_waitcnt vmcnt(8)" ::: "memory");
        else if (p == P - 3) asm volatile("s_waitcnt vmcnt(4)" ::: "memory");
        else if (p == P - 2) asm volatile("s_waitcnt vmcnt(0)" ::: "memory");
        if (p < P - 1) asm volatile("s_barrier" ::: "memory");
    }
#undef ISSUE_KH

    #pragma unroll
    for (int mi = 0; mi < 8; ++mi) {
        #pragma unroll
        for (int ni = 0; ni < 4; ++ni) {
            const int col = colb + wcp * 64 + ni * 16 + (ln & 15);
            #pragma unroll
            for (int rg = 0; rg < 4; ++rg) {
                const int r = row0 + wrp * 128 + mi * 16 + (ln >> 4) * 4 + rg;
                if (r < M) C[(size_t)r * N + col] = f2bf_(acc[mi][ni][rg]);
            }
        }
    }
}

// ---------------------------------------------------------------------------
__global__ void f2bf_vec(const float* __restrict__ src, unsigned short* __restrict__ dst, int n4)
{
    const int i = blockIdx.x * blockDim.x + threadIdx.x;
    if (i >= n4) return;
    const float4 v = ((const float4*)src)[i];
    ushort4 o;
    o.x = f2bf_(v.x); o.y = f2bf_(v.y); o.z = f2bf_(v.z); o.w = f2bf_(v.w);
    ((ushort4*)dst)[i] = o;
}

// wfxP[rp,:], rp = t*48 + g*16 + jj  <-  w_fioux row ((g+1)*1024 + t*16 + jj)
__global__ void build_wfxp(const float* __restrict__ w_fioux,
                           unsigned short* __restrict__ dst, int total4)
{
    const int idx = blockIdx.x * blockDim.x + threadIdx.x;
    if (idx >= total4) return;
    const int rp = idx >> 8;            // 0..3071
    const int c4 = (idx & 255) << 2;
    const int t  = rp / 48;
    const int q  = rp - t * 48;
    const int g  = q >> 4;
    const int jj = q & 15;
    const float* src = w_fioux + (size_t)((g + 1) * 1024 + t * 16 + jj) * 1024;
    const float4 v = *(const float4*)(src + c4);
    ushort4 o;
    o.x = f2bf_(v.x); o.y = f2bf_(v.y); o.z = f2bf_(v.z); o.w = f2bf_(v.w);
    *(ushort4*)(dst + (size_t)rp * 1024 + c4) = o;
}

// wcatP[rp,:], rp = t*80 + g*16 + jj  <-  gate-g weight row (t*16 + jj)
__global__ void build_wcatp(const float* __restrict__ w_iouh, const float* __restrict__ w_fh,
                            unsigned short* __restrict__ dst, int total4)
{
    const int idx = blockIdx.x * blockDim.x + threadIdx.x;
    if (idx >= total4) return;
    const int rp = idx >> 9;            // 0..5119
    const int c4 = (idx & 511) << 2;
    const int t  = rp / 80;
    const int q  = rp - t * 80;
    const int g  = q >> 4;
    const int jj = q & 15;
    const int srow = t * 16 + jj;
    const float* src = (g < 3) ? (w_iouh + (size_t)(g * 1024 + srow) * 2048)
                               : (w_fh   + (size_t)((g - 3) * 1024 + srow) * 2048);
    const float4 v = *(const float4*)(src + c4);
    ushort4 o;
    o.x = f2bf_(v.x); o.y = f2bf_(v.y); o.z = f2bf_(v.z); o.w = f2bf_(v.w);
    *(ushort4*)(dst + (size_t)rp * 2048 + c4) = o;
}

__device__ __forceinline__ void acc4_(float* v, ushort4 u) {
    v[0] += bf2f_(u.x); v[1] += bf2f_(u.y); v[2] += bf2f_(u.z); v[3] += bf2f_(u.w);
}

// g: S bf16 partials of [rows,5120] in wcatP period-80 order; c_prev [rows,2048].
__global__ void node_gates(const unsigned short* __restrict__ g, int S, size_t sstride,
                           const float* __restrict__ b,
                           const unsigned short* __restrict__ c_prev,
                           unsigned short* __restrict__ c_out,
                           unsigned short* __restrict__ h_bf,
                           float* __restrict__ h_f32, int rows)
{
    const int idx = blockIdx.x * blockDim.x + threadIdx.x;
    if (idx >= rows * 256) return;
    const int r = idx >> 8, q = (idx & 255) << 2;   // j = q..q+3
    const int t = q >> 4, jj = q & 15;
    float vi[4] = {}, vo[4] = {}, vu[4] = {}, vfl[4] = {}, vfr[4] = {};
    const unsigned short* gr = g + (size_t)r * 5120 + t * 80 + jj;
    for (int s = 0; s < S; ++s, gr += sstride) {
        acc4_(vi,  *(const ushort4*)(gr));
        acc4_(vo,  *(const ushort4*)(gr + 16));
        acc4_(vu,  *(const ushort4*)(gr + 32));
        acc4_(vfl, *(const ushort4*)(gr + 48));
        acc4_(vfr, *(const ushort4*)(gr + 64));
    }
    const float* bi = b + 1024 + q;
    const float* bo = b + 2048 + q;
    const float* bu = b + 3072 + q;
    const float* bff = b + q;
    const ushort4 clu = *(const ushort4*)(c_prev + (size_t)r * 2048 + q);
    const ushort4 cru = *(const ushort4*)(c_prev + (size_t)r * 2048 + 1024 + q);
    const float cl[4] = { bf2f_(clu.x), bf2f_(clu.y), bf2f_(clu.z), bf2f_(clu.w) };
    const float cr[4] = { bf2f_(cru.x), bf2f_(cru.y), bf2f_(cru.z), bf2f_(cru.w) };

    ushort4 co, ho;
    float cv[4], hv[4];
    #pragma unroll
    for (int e = 0; e < 4; ++e) {
        const float c = sig_(vi[e] + bi[e]) * tanhf(vu[e] + bu[e])
                      + sig_(vfl[e] + bff[e]) * cl[e]
                      + sig_(vfr[e] + bff[e]) * cr[e];
        cv[e] = c;
        hv[e] = sig_(vo[e] + bo[e]) * tanhf(c);
    }
    co.x = f2bf_(cv[0]); co.y = f2bf_(cv[1]); co.z = f2bf_(cv[2]); co.w = f2bf_(cv[3]);
    ho.x = f2bf_(hv[0]); ho.y = f2bf_(hv[1]); ho.z = f2bf_(hv[2]); ho.w = f2bf_(hv[3]);
    *(ushort4*)(c_out + (size_t)r * 1024 + q) = co;
    *(ushort4*)(h_bf + (size_t)r * 1024 + q) = ho;
    if (h_f32) {
        float4 hf; hf.x = hv[0]; hf.y = hv[1]; hf.z = hv[2]; hf.w = hv[3];
        *(float4*)(h_f32 + (size_t)r * 1024 + q) = hf;
    }
}

extern "C" void kernel_launch(void* const* d_in, const int* in_sizes, int n_in,
                              void* d_out, int out_size, void* d_ws, size_t ws_size,
                              hipStream_t stream)
{
    const float* inputs  = (const float*)d_in[0];  // [16384,1024]
    const float* w_fioux = (const float*)d_in[1];  // [4096,1024]
    const float* b_fioux = (const float*)d_in[2];  // [4096]
    const float* w_iouh  = (const float*)d_in[3];  // [3072,2048]
    const float* w_fh    = (const float*)d_in[4];  // [2048,2048]
    float* out = (float*)d_out;                    // [32,1024]

    // ---- ws layout, bf16 units (228.6 MB, proven size) ----
    unsigned short* us    = (unsigned short*)d_ws;
    unsigned short* c_a   = us;                          // 16777216
    unsigned short* c_b   = c_a + (size_t)16777216;      //  8388608
    unsigned short* h_a   = c_b + (size_t)8388608;       // 16777216
    unsigned short* h_b   = h_a + (size_t)16777216;      //  8388608
    unsigned short* wfxP  = h_b + (size_t)8388608;       //  3145728
    unsigned short* wcatP = wfxP + (size_t)3145728;      // 10485760
    unsigned short* gbuf  = wcatP + (size_t)10485760;    // 50331648 (tail only)
    unsigned short* x_bf  = gbuf;  // x lives in gbuf region (dead before tail);
                                   // must NOT alias c_a (leaf reads x, writes c_a)

    // ---- one-time conversions / weight permutes ----
    f2bf_vec<<<16384, 256, 0, stream>>>(inputs, x_bf, 4194304);
    build_wfxp<<<3072, 256, 0, stream>>>(w_fioux, wfxP, 786432);
    build_wcatp<<<10240, 256, 0, stream>>>(w_iouh, w_fh, wcatP, 5120 * 512);

    // ---- fused leaf: 16384 rows, K=1024, block 128x192 ----
    gemm_leaff<<<dim3(16, 128), 256, 0, stream>>>(x_bf, wfxP, b_fioux, c_a, h_a);

    // ---- fused internal levels: n = 256, 128, 64 (block 256x320, 4-wave) ----
    unsigned short *hp = h_a, *cp = c_a, *hn = h_b, *cn = c_b;
    for (int n = 256; n >= 64; n >>= 1) {
        const int m = 32 * n;
        gemm320w<<<dim3(16, m / 256), 256, 0, stream>>>(hp, wcatP, b_fioux, cp, cn, hn, m);
        unsigned short* t;
        t = hp; hp = hn; hn = t;
        t = cp; cp = cn; cn = t;
    }

    // ---- tail levels: n = 32 .. 1, split-K + node_gates ----
    for (int n = 32; n >= 1; n >>= 1) {
        const int m = 32 * n;
        const int S = (m >= 512) ? 4 : 8;
        const int Klen = 2048 / S;
        gemm256<<<dim3(20, (m + 255) / 256, S), 512, 0, stream>>>(
            hp, wcatP, gbuf, m, 5120, 2048, Klen);
        node_gates<<<m, 256, 0, stream>>>(
            gbuf, S, (size_t)m * 5120, b_fioux, cp, cn, hn,
            (n == 1) ? out : nullptr, m);
        unsigned short* t;
        t = hp; hp = hn; hn = t;
        t = cp; cp = cn; cn = t;
    }
    (void)in_sizes; (void)n_in; (void)out_size; (void)ws_size;
}

// Round 12
// 681.759 us; speedup vs baseline: 5.7792x; 5.7792x over previous
//
#include <hip/hip_runtime.h>
#include <cstdint>
#include <cstddef>

// BinaryTreeLSTM — best-of-measured hybrid (round 12 = revert of r11 spill).
// Leaf:  gemm_leaff (round-9 proven: 4-wave, 2 blocks/CU, period-48 wfxP).
// Nodes: gemm320f (round-8 proven: 8-wave 256x320, period-320 wcatP,
//        vmcnt ladder 10/8 -> 5/4 -> 0, W-stationary XCD decode).
// Tail:  gemm256 split-K (bf16 partials) + node_gates (period-320 order).

typedef __attribute__((ext_vector_type(8))) short bf16x8;
typedef __attribute__((ext_vector_type(4))) float f32x4;

__device__ __forceinline__ float sig_(float x) { return 1.0f / (1.0f + __expf(-x)); }

__device__ __forceinline__ unsigned short f2bf_(float x) {
    union { float f; uint32_t u; } v; v.f = x;
    uint32_t r = v.u + 0x7fffu + ((v.u >> 16) & 1u);   // RNE
    return (unsigned short)(r >> 16);
}
__device__ __forceinline__ float bf2f_(unsigned short u) {
    union { uint32_t u; float f; } v; v.u = ((uint32_t)u) << 16; return v.f;
}

#define GL16(g, l) __builtin_amdgcn_global_load_lds( \
    (const __attribute__((address_space(1))) void*)(g), \
    (__attribute__((address_space(3))) void*)(l), 16, 0, 0)

// ---------------------------------------------------------------------------
// gemm320f: fused internal level (ROUND-8 VERBATIM). A[M,2048]bf16,
// Wp[5120,2048]bf16 period-320 (16 groups of 320 rows = [ih|oh|uh|fl|fr] for
// 64 consecutive j). Block 256x320, 8 waves (2Mx4N). acc[8][5].
// Waves 0-3 carry 5 loads/phase (vmcnt 10/5/0), waves 4-7 carry 4 (8/4/0).
// W-stationary decode: gx=16 -> 2 bx per XCD.
// ---------------------------------------------------------------------------
__global__ __launch_bounds__(512, 2)
void gemm320f(const unsigned short* __restrict__ A,
              const unsigned short* __restrict__ Wp,
              const float* __restrict__ b,
              const unsigned short* __restrict__ c_prev,
              unsigned short* __restrict__ c_out,
              unsigned short* __restrict__ h_out,
              int M)
{
    __shared__ unsigned short lA[4 * 8192];    // 64 KB
    __shared__ unsigned short lB[4 * 10240];   // 80 KB
    const int lda = 2048;

    const int orig = blockIdx.x + 16 * blockIdx.y;
    const int xcd  = orig & 7;
    const int pos  = orig >> 3;
    const int bx   = xcd * 2 + (pos & 1);
    const int by   = pos >> 1;

    const int tid = threadIdx.x;
    const int ln  = tid & 63;
    const int wv  = tid >> 6;
    const int wrp = wv >> 2;
    const int wcp = wv & 3;
    const int row0 = by * 256;
    const int colb = bx * 320;
    const bool five = (wv < 4);      // wave-uniform: carries the 5th B load

    const int rowS = tid >> 2;
    const int gS   = (tid & 3) ^ ((tid >> 3) & 3);
    const unsigned short* a0 = A + (size_t)min(row0 + rowS,       M - 1) * lda + gS * 8;
    const unsigned short* a1 = A + (size_t)min(row0 + rowS + 128, M - 1) * lda + gS * 8;
    const unsigned short* w0 = Wp + (size_t)(colb + rowS)       * lda + gS * 8;
    const unsigned short* w1 = Wp + (size_t)(colb + rowS + 128) * lda + gS * 8;
    const unsigned short* w2 = Wp + (size_t)(colb + 256 + ((tid & 255) >> 2)) * lda + gS * 8;
    const int ld0 = tid * 8;
    const int ld1 = tid * 8 + 4096;
    const int ld2 = (tid & 255) * 8 + 8192;

    int offA[8], offB[5];
    #pragma unroll
    for (int i = 0; i < 8; ++i) {
        const int r = wrp * 128 + i * 16 + (ln & 15);
        offA[i] = r * 32 + ((ln >> 4) ^ ((r >> 1) & 3)) * 8;
    }
    #pragma unroll
    for (int g = 0; g < 5; ++g) {
        const int r = g * 64 + wcp * 16 + (ln & 15);
        offB[g] = r * 32 + ((ln >> 4) ^ ((r >> 1) & 3)) * 8;
    }

    f32x4 acc[8][5] = {};
    const int P = 64;   // 2048 / 32

#define ISSUE_F(kh) do { \
    const int _sl = (kh) & 3; \
    const size_t _ko = (size_t)(kh) * 32; \
    GL16(a0 + _ko, lA + _sl * 8192 + ld0); \
    GL16(a1 + _ko, lA + _sl * 8192 + ld1); \
    GL16(w0 + _ko, lB + _sl * 10240 + ld0); \
    GL16(w1 + _ko, lB + _sl * 10240 + ld1); \
    if (five) GL16(w2 + _ko, lB + _sl * 10240 + ld2); \
} while (0)

    ISSUE_F(0); ISSUE_F(1); ISSUE_F(2);
    if (five) asm volatile("s_waitcnt vmcnt(10)" ::: "memory");
    else      asm volatile("s_waitcnt vmcnt(8)"  ::: "memory");
    asm volatile("s_barrier" ::: "memory");

    for (int p = 0; p < P; ++p) {
        const unsigned short* pa = lA + (p & 3) * 8192;
        const unsigned short* pb = lB + (p & 3) * 10240;
        bf16x8 bf[5], af[4], ag[4];
        #pragma unroll
        for (int g = 0; g < 5; ++g) bf[g] = *(const bf16x8*)(pb + offB[g]);
        #pragma unroll
        for (int i = 0; i < 4; ++i) af[i] = *(const bf16x8*)(pa + offA[i]);
        #pragma unroll
        for (int i = 0; i < 4; ++i) ag[i] = *(const bf16x8*)(pa + offA[4 + i]);
        if (p <= P - 4) ISSUE_F(p + 3);
        __builtin_amdgcn_s_setprio(1);
        #pragma unroll
        for (int m = 0; m < 4; ++m)
            #pragma unroll
            for (int g = 0; g < 5; ++g)
                acc[m][g] = __builtin_amdgcn_mfma_f32_16x16x32_bf16(af[m], bf[g], acc[m][g], 0, 0, 0);
        #pragma unroll
        for (int m = 0; m < 4; ++m)
            #pragma unroll
            for (int g = 0; g < 5; ++g)
                acc[4 + m][g] = __builtin_amdgcn_mfma_f32_16x16x32_bf16(ag[m], bf[g], acc[4 + m][g], 0, 0, 0);
        __builtin_amdgcn_s_setprio(0);
        if (p <= P - 4) {
            if (five) asm volatile("s_waitcnt vmcnt(10)" ::: "memory");
            else      asm volatile("s_waitcnt vmcnt(8)"  ::: "memory");
        } else if (p == P - 3) {
            if (five) asm volatile("s_waitcnt vmcnt(5)" ::: "memory");
            else      asm volatile("s_waitcnt vmcnt(4)" ::: "memory");
        } else if (p == P - 2) {
            asm volatile("s_waitcnt vmcnt(0)" ::: "memory");
        }
        if (p < P - 1) asm volatile("s_barrier" ::: "memory");
    }
#undef ISSUE_F

    // ---- fused gate epilogue ----
    const int jg = bx * 64 + wcp * 16 + (ln & 15);   // global j in [0,1024)
    const float bi = b[1024 + jg];
    const float bo = b[2048 + jg];
    const float bu = b[3072 + jg];
    const float bff = b[jg];
    #pragma unroll
    for (int mi = 0; mi < 8; ++mi) {
        #pragma unroll
        for (int rg = 0; rg < 4; ++rg) {
            const int r = row0 + wrp * 128 + mi * 16 + (ln >> 4) * 4 + rg;
            if (r < M) {
                const float cl = bf2f_(c_prev[(size_t)r * 2048 + jg]);
                const float cr = bf2f_(c_prev[(size_t)r * 2048 + 1024 + jg]);
                const float iv = sig_(acc[mi][0][rg] + bi);
                const float ov = sig_(acc[mi][1][rg] + bo);
                const float uv = tanhf(acc[mi][2][rg] + bu);
                const float flv = sig_(acc[mi][3][rg] + bff);
                const float frv = sig_(acc[mi][4][rg] + bff);
                const float c = iv * uv + flv * cl + frv * cr;
                const float h = ov * tanhf(c);
                c_out[(size_t)r * 1024 + jg] = f2bf_(c);
                h_out[(size_t)r * 1024 + jg] = f2bf_(h);
            }
        }
    }
}

// ---------------------------------------------------------------------------
// gemm_leaff: fused LEAF (round-9 verbatim). Wp period-48. Block 128x192,
// 4 waves, LDS 60 KB -> 2 blocks/CU. 3 slots, lookahead 2.
// ---------------------------------------------------------------------------
__global__ __launch_bounds__(256, 2)
void gemm_leaff(const unsigned short* __restrict__ A,
                const unsigned short* __restrict__ Wp,
                const float* __restrict__ b,
                unsigned short* __restrict__ c_out,
                unsigned short* __restrict__ h_out)
{
    __shared__ unsigned short lA[3 * 4096];   // 24 KB
    __shared__ unsigned short lB[3 * 6144];   // 36 KB
    const int lda = 1024;

    const int orig = blockIdx.x + 16 * blockIdx.y;
    const int xcd  = orig & 7;
    const int pos  = orig >> 3;
    const int bx   = xcd * 2 + (pos & 1);
    const int by   = pos >> 1;

    if ((pos >> 5) & 1) asm volatile("s_sleep 10" ::: "memory");

    const int tid = threadIdx.x;
    const int ln  = tid & 63;
    const int wv  = tid >> 6;
    const int wrp = wv >> 1;
    const int wcp = wv & 1;
    const int row0 = by * 128;
    const int colb = bx * 192;

    const int rowS = tid >> 2;
    const int gS   = (tid & 3) ^ ((tid >> 3) & 3);
    const unsigned short* a0 = A + (size_t)(row0 + rowS) * lda + gS * 8;
    const unsigned short* a1 = a0 + (size_t)64 * lda;
    const unsigned short* w0 = Wp + (size_t)(colb + rowS) * lda + gS * 8;
    const unsigned short* w1 = w0 + (size_t)64 * lda;
    const unsigned short* w2 = w0 + (size_t)128 * lda;
    const int ld0 = tid * 8;

    int offA[4], offB[6];
    #pragma unroll
    for (int i = 0; i < 4; ++i) {
        const int r = wrp * 64 + i * 16 + (ln & 15);
        offA[i] = r * 32 + ((ln >> 4) ^ ((r >> 1) & 3)) * 8;
    }
    #pragma unroll
    for (int grp = 0; grp < 2; ++grp)
        #pragma unroll
        for (int g = 0; g < 3; ++g) {
            const int r = wcp * 96 + grp * 48 + g * 16 + (ln & 15);
            offB[grp * 3 + g] = r * 32 + ((ln >> 4) ^ ((r >> 1) & 3)) * 8;
        }

    f32x4 acc[4][6] = {};
    const int P = 32;   // K = 1024

#define ISSUE_L(sl, kh) do { \
    const size_t _ko = (size_t)(kh) * 32; \
    GL16(a0 + _ko, lA + (sl) * 4096 + ld0); \
    GL16(a1 + _ko, lA + (sl) * 4096 + 2048 + ld0); \
    GL16(w0 + _ko, lB + (sl) * 6144 + ld0); \
    GL16(w1 + _ko, lB + (sl) * 6144 + 2048 + ld0); \
    GL16(w2 + _ko, lB + (sl) * 6144 + 4096 + ld0); \
} while (0)

    ISSUE_L(0, 0); ISSUE_L(1, 1);
    asm volatile("s_waitcnt vmcnt(5)" ::: "memory");
    asm volatile("s_barrier" ::: "memory");

    int rd = 0, is = 2;
    for (int p = 0; p < P; ++p) {
        const unsigned short* pa = lA + rd * 4096;
        const unsigned short* pb = lB + rd * 6144;
        bf16x8 bf[6], af[4];
        #pragma unroll
        for (int g = 0; g < 6; ++g) bf[g] = *(const bf16x8*)(pb + offB[g]);
        #pragma unroll
        for (int i = 0; i < 4; ++i) af[i] = *(const bf16x8*)(pa + offA[i]);
        if (p <= P - 3) ISSUE_L(is, p + 2);
        __builtin_amdgcn_s_setprio(1);
        #pragma unroll
        for (int m = 0; m < 4; ++m)
            #pragma unroll
            for (int g = 0; g < 6; ++g)
                acc[m][g] = __builtin_amdgcn_mfma_f32_16x16x32_bf16(af[m], bf[g], acc[m][g], 0, 0, 0);
        __builtin_amdgcn_s_setprio(0);
        if (p <= P - 3)      asm volatile("s_waitcnt vmcnt(5)" ::: "memory");
        else if (p == P - 2) asm volatile("s_waitcnt vmcnt(0)" ::: "memory");
        if (p < P - 1) asm volatile("s_barrier" ::: "memory");
        rd = (rd == 2) ? 0 : rd + 1;
        is = (is == 2) ? 0 : is + 1;
    }
#undef ISSUE_L

    #pragma unroll
    for (int grp = 0; grp < 2; ++grp) {
        const int j = bx * 64 + wcp * 32 + grp * 16 + (ln & 15);
        const float bi = b[1024 + j];
        const float bo = b[2048 + j];
        const float bu = b[3072 + j];
        #pragma unroll
        for (int mi = 0; mi < 4; ++mi) {
            #pragma unroll
            for (int rg = 0; rg < 4; ++rg) {
                const int r = row0 + wrp * 64 + mi * 16 + (ln >> 4) * 4 + rg;
                const float cv = sig_(acc[mi][grp * 3 + 0][rg] + bi) * tanhf(acc[mi][grp * 3 + 2][rg] + bu);
                const float hv = sig_(acc[mi][grp * 3 + 1][rg] + bo) * tanhf(cv);
                c_out[(size_t)r * 1024 + j] = f2bf_(cv);
                h_out[(size_t)r * 1024 + j] = f2bf_(hv);
            }
        }
    }
}

// ---------------------------------------------------------------------------
// gemm256: tail split-K. partial[bz][M,N] bf16 = A[M,kr] @ W[N,kr]^T.
// ---------------------------------------------------------------------------
__global__ __launch_bounds__(512, 2)
void gemm256(const unsigned short* __restrict__ A,
             const unsigned short* __restrict__ W,
             unsigned short* __restrict__ C, int M, int N, int lda, int Klen)
{
    __shared__ unsigned short lA[4 * 8192];   // 64 KB
    __shared__ unsigned short lB[4 * 8192];   // 64 KB

    const int gx = gridDim.x, gy = gridDim.y;
    int id = blockIdx.x + gx * (blockIdx.y + gy * blockIdx.z);
    {
        const int nwg = gx * gy * gridDim.z;
        const int q = nwg >> 3, r = nwg & 7, x = id & 7, i = id >> 3;
        id = (x < r ? x * (q + 1) : r * (q + 1) + (x - r) * q) + i;
    }
    const int bz  = id / (gx * gy);
    const int rem = id - bz * gx * gy;
    const int by  = rem / gx;
    const int bx  = rem - by * gx;

    const int tid = threadIdx.x;
    const int ln  = tid & 63;
    const int wv  = tid >> 6;
    const int wrp = wv >> 2;
    const int wcp = wv & 3;
    const int row0 = by * 256;
    const int colb = bx * 256;
    const int kbase = bz * Klen;
    C += (size_t)bz * M * N;

    const int rowS = tid >> 2;
    const int gS   = (tid & 3) ^ ((tid >> 3) & 3);
    const unsigned short* a0 = A + (size_t)min(row0 + rowS,       M - 1) * lda + kbase + gS * 8;
    const unsigned short* a1 = A + (size_t)min(row0 + rowS + 128, M - 1) * lda + kbase + gS * 8;
    const unsigned short* b0 = W + (size_t)(colb + rowS)       * lda + kbase + gS * 8;
    const unsigned short* b1 = W + (size_t)(colb + rowS + 128) * lda + kbase + gS * 8;
    const int ld0 = tid * 8;
    const int ld1 = tid * 8 + 4096;

    int offA[8], offB[4];
    #pragma unroll
    for (int i = 0; i < 8; ++i) {
        const int r = wrp * 128 + i * 16 + (ln & 15);
        offA[i] = r * 32 + ((ln >> 4) ^ ((r >> 1) & 3)) * 8;
    }
    #pragma unroll
    for (int i = 0; i < 4; ++i) {
        const int r = wcp * 64 + i * 16 + (ln & 15);
        offB[i] = r * 32 + ((ln >> 4) ^ ((r >> 1) & 3)) * 8;
    }

    f32x4 acc[8][4] = {};
    const int P = Klen >> 5;

#define ISSUE_KH(kh) do { \
    const int _sl = (kh) & 3; \
    const size_t _ko = (size_t)(kh) * 32; \
    GL16(a0 + _ko, lA + _sl * 8192 + ld0); \
    GL16(a1 + _ko, lA + _sl * 8192 + ld1); \
    GL16(b0 + _ko, lB + _sl * 8192 + ld0); \
    GL16(b1 + _ko, lB + _sl * 8192 + ld1); \
} while (0)

    ISSUE_KH(0); ISSUE_KH(1); ISSUE_KH(2);
    asm volatile("s_waitcnt vmcnt(8)" ::: "memory");
    asm volatile("s_barrier" ::: "memory");

    for (int p = 0; p < P; ++p) {
        const unsigned short* pa = lA + (p & 3) * 8192;
        const unsigned short* pb = lB + (p & 3) * 8192;
        bf16x8 bf[4], af[4], ag[4];
        #pragma unroll
        for (int i = 0; i < 4; ++i) bf[i] = *(const bf16x8*)(pb + offB[i]);
        #pragma unroll
        for (int i = 0; i < 4; ++i) af[i] = *(const bf16x8*)(pa + offA[i]);
        #pragma unroll
        for (int i = 0; i < 4; ++i) ag[i] = *(const bf16x8*)(pa + offA[4 + i]);
        if (p <= P - 4) ISSUE_KH(p + 3);
        __builtin_amdgcn_s_setprio(1);
        #pragma unroll
        for (int m = 0; m < 4; ++m)
            #pragma unroll
            for (int n = 0; n < 4; ++n)
                acc[m][n] = __builtin_amdgcn_mfma_f32_16x16x32_bf16(af[m], bf[n], acc[m][n], 0, 0, 0);
        #pragma unroll
        for (int m = 0; m < 4; ++m)
            #pragma unroll
            for (int n = 0; n < 4; ++n)
                acc[4 + m][n] = __builtin_amdgcn_mfma_f32_16x16x32_bf16(ag[m], bf[n], acc[4 + m][n], 0, 0, 0);
        __builtin_amdgcn_s_setprio(0);
        if (p <= P - 4)      asm volatile("s_waitcnt vmcnt(8)" ::: "memory");
        else if (p == P - 3) asm volatile("s_waitcnt vmcnt(4)" ::: "memory");
        else if (p == P - 2) asm volatile("s_waitcnt vmcnt(0)" ::: "memory");
        if (p < P - 1) asm volatile("s_barrier" ::: "memory");
    }
#undef ISSUE_KH

    #pragma unroll
    for (int mi = 0; mi < 8; ++mi) {
        #pragma unroll
        for (int ni = 0; ni < 4; ++ni) {
            const int col = colb + wcp * 64 + ni * 16 + (ln & 15);
            #pragma unroll
            for (int rg = 0; rg < 4; ++rg) {
                const int r = row0 + wrp * 128 + mi * 16 + (ln >> 4) * 4 + rg;
                if (r < M) C[(size_t)r * N + col] = f2bf_(acc[mi][ni][rg]);
            }
        }
    }
}

// ---------------------------------------------------------------------------
__global__ void f2bf_vec(const float* __restrict__ src, unsigned short* __restrict__ dst, int n4)
{
    const int i = blockIdx.x * blockDim.x + threadIdx.x;
    if (i >= n4) return;
    const float4 v = ((const float4*)src)[i];
    ushort4 o;
    o.x = f2bf_(v.x); o.y = f2bf_(v.y); o.z = f2bf_(v.z); o.w = f2bf_(v.w);
    ((ushort4*)dst)[i] = o;
}

// wfxP[rp,:], rp = t*48 + g*16 + jj  <-  w_fioux row ((g+1)*1024 + t*16 + jj)
__global__ void build_wfxp(const float* __restrict__ w_fioux,
                           unsigned short* __restrict__ dst, int total4)
{
    const int idx = blockIdx.x * blockDim.x + threadIdx.x;
    if (idx >= total4) return;
    const int rp = idx >> 8;            // 0..3071
    const int c4 = (idx & 255) << 2;
    const int t  = rp / 48;
    const int q  = rp - t * 48;
    const int g  = q >> 4;
    const int jj = q & 15;
    const float* src = w_fioux + (size_t)((g + 1) * 1024 + t * 16 + jj) * 1024;
    const float4 v = *(const float4*)(src + c4);
    ushort4 o;
    o.x = f2bf_(v.x); o.y = f2bf_(v.y); o.z = f2bf_(v.z); o.w = f2bf_(v.w);
    *(ushort4*)(dst + (size_t)rp * 1024 + c4) = o;
}

// wcatP[rp,:], rp = t*320 + g*64 + jj  <-  gate-g weight row (t*64 + jj)
__global__ void build_wcatp(const float* __restrict__ w_iouh, const float* __restrict__ w_fh,
                            unsigned short* __restrict__ dst, int total4)
{
    const int idx = blockIdx.x * blockDim.x + threadIdx.x;
    if (idx >= total4) return;
    const int rp = idx >> 9;            // 0..5119
    const int c4 = (idx & 511) << 2;
    const int t  = rp / 320;
    const int q  = rp - t * 320;
    const int g  = q >> 6;
    const int jj = q & 63;
    const int srow = t * 64 + jj;
    const float* src = (g < 3) ? (w_iouh + (size_t)(g * 1024 + srow) * 2048)
                               : (w_fh   + (size_t)((g - 3) * 1024 + srow) * 2048);
    const float4 v = *(const float4*)(src + c4);
    ushort4 o;
    o.x = f2bf_(v.x); o.y = f2bf_(v.y); o.z = f2bf_(v.z); o.w = f2bf_(v.w);
    *(ushort4*)(dst + (size_t)rp * 2048 + c4) = o;
}

__device__ __forceinline__ void acc4_(float* v, ushort4 u) {
    v[0] += bf2f_(u.x); v[1] += bf2f_(u.y); v[2] += bf2f_(u.z); v[3] += bf2f_(u.w);
}

// g: S bf16 partials of [rows,5120] in wcatP period-320 order (16 groups of
// [ih64|oh64|uh64|fl64|fr64]); c_prev bf16 [rows,2048].
__global__ void node_gates(const unsigned short* __restrict__ g, int S, size_t sstride,
                           const float* __restrict__ b,
                           const unsigned short* __restrict__ c_prev,
                           unsigned short* __restrict__ c_out,
                           unsigned short* __restrict__ h_bf,
                           float* __restrict__ h_f32, int rows)
{
    const int idx = blockIdx.x * blockDim.x + threadIdx.x;
    if (idx >= rows * 256) return;
    const int r = idx >> 8, q = (idx & 255) << 2;   // j = q..q+3
    const int t = q >> 6, jj = q & 63;
    float vi[4] = {}, vo[4] = {}, vu[4] = {}, vfl[4] = {}, vfr[4] = {};
    const unsigned short* gr = g + (size_t)r * 5120 + t * 320 + jj;
    for (int s = 0; s < S; ++s, gr += sstride) {
        acc4_(vi,  *(const ushort4*)(gr));
        acc4_(vo,  *(const ushort4*)(gr + 64));
        acc4_(vu,  *(const ushort4*)(gr + 128));
        acc4_(vfl, *(const ushort4*)(gr + 192));
        acc4_(vfr, *(const ushort4*)(gr + 256));
    }
    const float* bi = b + 1024 + q;
    const float* bo = b + 2048 + q;
    const float* bu = b + 3072 + q;
    const float* bff = b + q;
    const ushort4 clu = *(const ushort4*)(c_prev + (size_t)r * 2048 + q);
    const ushort4 cru = *(const ushort4*)(c_prev + (size_t)r * 2048 + 1024 + q);
    const float cl[4] = { bf2f_(clu.x), bf2f_(clu.y), bf2f_(clu.z), bf2f_(clu.w) };
    const float cr[4] = { bf2f_(cru.x), bf2f_(cru.y), bf2f_(cru.z), bf2f_(cru.w) };

    ushort4 co, ho;
    float cv[4], hv[4];
    #pragma unroll
    for (int e = 0; e < 4; ++e) {
        const float c = sig_(vi[e] + bi[e]) * tanhf(vu[e] + bu[e])
                      + sig_(vfl[e] + bff[e]) * cl[e]
                      + sig_(vfr[e] + bff[e]) * cr[e];
        cv[e] = c;
        hv[e] = sig_(vo[e] + bo[e]) * tanhf(c);
    }
    co.x = f2bf_(cv[0]); co.y = f2bf_(cv[1]); co.z = f2bf_(cv[2]); co.w = f2bf_(cv[3]);
    ho.x = f2bf_(hv[0]); ho.y = f2bf_(hv[1]); ho.z = f2bf_(hv[2]); ho.w = f2bf_(hv[3]);
    *(ushort4*)(c_out + (size_t)r * 1024 + q) = co;
    *(ushort4*)(h_bf + (size_t)r * 1024 + q) = ho;
    if (h_f32) {
        float4 hf; hf.x = hv[0]; hf.y = hv[1]; hf.z = hv[2]; hf.w = hv[3];
        *(float4*)(h_f32 + (size_t)r * 1024 + q) = hf;
    }
}

extern "C" void kernel_launch(void* const* d_in, const int* in_sizes, int n_in,
                              void* d_out, int out_size, void* d_ws, size_t ws_size,
                              hipStream_t stream)
{
    const float* inputs  = (const float*)d_in[0];  // [16384,1024]
    const float* w_fioux = (const float*)d_in[1];  // [4096,1024]
    const float* b_fioux = (const float*)d_in[2];  // [4096]
    const float* w_iouh  = (const float*)d_in[3];  // [3072,2048]
    const float* w_fh    = (const float*)d_in[4];  // [2048,2048]
    float* out = (float*)d_out;                    // [32,1024]

    // ---- ws layout, bf16 units (228.6 MB, proven size) ----
    unsigned short* us    = (unsigned short*)d_ws;
    unsigned short* c_a   = us;                          // 16777216
    unsigned short* c_b   = c_a + (size_t)16777216;      //  8388608
    unsigned short* h_a   = c_b + (size_t)8388608;       // 16777216
    unsigned short* h_b   = h_a + (size_t)16777216;      //  8388608
    unsigned short* wfxP  = h_b + (size_t)8388608;       //  3145728
    unsigned short* wcatP = wfxP + (size_t)3145728;      // 10485760
    unsigned short* gbuf  = wcatP + (size_t)10485760;    // 50331648 (tail only)
    unsigned short* x_bf  = gbuf;  // x lives in gbuf region (dead before tail);
                                   // must NOT alias c_a (leaf reads x, writes c_a)

    // ---- one-time conversions / weight permutes ----
    f2bf_vec<<<16384, 256, 0, stream>>>(inputs, x_bf, 4194304);
    build_wfxp<<<3072, 256, 0, stream>>>(w_fioux, wfxP, 786432);
    build_wcatp<<<10240, 256, 0, stream>>>(w_iouh, w_fh, wcatP, 5120 * 512);

    // ---- fused leaf: 16384 rows, K=1024, block 128x192 ----
    gemm_leaff<<<dim3(16, 128), 256, 0, stream>>>(x_bf, wfxP, b_fioux, c_a, h_a);

    // ---- fused internal levels: n = 256, 128, 64 (block 256x320, 8-wave) ----
    unsigned short *hp = h_a, *cp = c_a, *hn = h_b, *cn = c_b;
    for (int n = 256; n >= 64; n >>= 1) {
        const int m = 32 * n;
        gemm320f<<<dim3(16, m / 256), 512, 0, stream>>>(hp, wcatP, b_fioux, cp, cn, hn, m);
        unsigned short* t;
        t = hp; hp = hn; hn = t;
        t = cp; cp = cn; cn = t;
    }

    // ---- tail levels: n = 32 .. 1, split-K + node_gates ----
    for (int n = 32; n >= 1; n >>= 1) {
        const int m = 32 * n;
        const int S = (m >= 512) ? 4 : 8;
        const int Klen = 2048 / S;
        gemm256<<<dim3(20, (m + 255) / 256, S), 512, 0, stream>>>(
            hp, wcatP, gbuf, m, 5120, 2048, Klen);
        node_gates<<<m, 256, 0, stream>>>(
            gbuf, S, (size_t)m * 5120, b_fioux, cp, cn, hn,
            (n == 1) ? out : nullptr, m);
        unsigned short* t;
        t = hp; hp = hn; hn = t;
        t = cp; cp = cn; cn = t;
    }
    (void)in_sizes; (void)n_in; (void)out_size; (void)ws_size;
}